// Round 1
// baseline (465.222 us; speedup 1.0000x reference)
//
#include <hip/hip_runtime.h>

#define ROWS 8192
#define COLS 8192
#define TPB  256
#define EPT  32   // elements per thread (COLS / TPB)
#define VPT  8    // float4 chunks per thread

// Monotonic float->uint key: order of keys == order of floats.
__device__ __forceinline__ unsigned f2k(float x) {
    unsigned u = __float_as_uint(x);
    return (u & 0x80000000u) ? ~u : (u | 0x80000000u);
}
__device__ __forceinline__ float k2f(unsigned k) {
    unsigned u = (k & 0x80000000u) ? (k & 0x7FFFFFFFu) : ~k;
    return __uint_as_float(u);
}

__global__ __launch_bounds__(TPB, 4)
void rsoftmax_kernel(const float* __restrict__ in,
                     const float* __restrict__ rate_p,
                     float* __restrict__ out)
{
    const int t   = threadIdx.x;
    const int row = blockIdx.x;
    const float4* in4  = (const float4*)(in  + (size_t)row * COLS);
    float4*       out4 = (float4*)      (out + (size_t)row * COLS);

    // ---- load this thread's 32 elements into registers as ordered keys ----
    unsigned key[EPT];
    #pragma unroll
    for (int j = 0; j < VPT; ++j) {
        float4 v = in4[t + j * TPB];           // coalesced 16B/lane
        key[4*j+0] = f2k(v.x);
        key[4*j+1] = f2k(v.y);
        key[4*j+2] = f2k(v.z);
        key[4*j+3] = f2k(v.w);
    }

    // ---- rank to select: thresh = sorted_desc[idx], i.e. (idx+1)-th largest ----
    float rate = rate_p[0];
    rate = fminf(fmaxf(rate, 0.0f), 1.0f);
    int idx = (int)(rate * (float)COLS);       // trunc, like astype(int32)
    if (idx > COLS - 1) idx = COLS - 1;        // jnp.take clips
    if (idx < 0) idx = 0;

    __shared__ unsigned sHist[256];
    __shared__ unsigned sScan[256];
    __shared__ unsigned sK, sPfx;
    __shared__ float    sW[4];
    __shared__ float    sInv;

    if (t == 0) { sK = (unsigned)(idx + 1); sPfx = 0u; }
    __syncthreads();

    // ---- MSB-first 4x8-bit radix select for the k-th largest key ----
    #pragma unroll
    for (int pass = 0; pass < 4; ++pass) {
        const int      s      = 24 - 8 * pass;
        const unsigned himask = (pass == 0) ? 0u : (0xFFFFFFFFu << (s + 8));

        sHist[t] = 0u;
        __syncthreads();
        const unsigned pfx = sPfx;
        const unsigned kk  = sK;

        #pragma unroll
        for (int j = 0; j < EPT; ++j) {
            if (((key[j] ^ pfx) & himask) == 0u)
                atomicAdd(&sHist[(key[j] >> s) & 0xFFu], 1u);
        }
        __syncthreads();

        // inclusive suffix sum over 256 bins: sScan[b] = #elems with digit >= b
        sScan[t] = sHist[t];
        __syncthreads();
        #pragma unroll
        for (int off = 1; off < 256; off <<= 1) {
            unsigned v = (t + off < 256) ? sScan[t + off] : 0u;
            __syncthreads();
            sScan[t] += v;
            __syncthreads();
        }

        // unique bin b with sScan[b] >= kk > sScan[b+1]
        unsigned st = sScan[t];
        unsigned sn = (t == 255) ? 0u : sScan[t + 1];
        if (st >= kk && sn < kk) {
            sPfx = pfx | ((unsigned)t << s);
            sK   = kk - sn;
        }
        __syncthreads();
    }

    const float thr = k2f(sPfx);

    // ---- partial sums of relu(x - thr) * exp(x) ----
    float lsum = 0.0f;
    #pragma unroll
    for (int j = 0; j < EPT; ++j) {
        float x = k2f(key[j]);
        float w = fmaxf(x - thr, 0.0f);
        lsum += w * __expf(x);
    }
    #pragma unroll
    for (int off = 32; off > 0; off >>= 1)
        lsum += __shfl_down(lsum, off, 64);
    if ((t & 63) == 0) sW[t >> 6] = lsum;
    __syncthreads();
    if (t == 0) sInv = 1.0f / (sW[0] + sW[1] + sW[2] + sW[3]);
    __syncthreads();
    const float inv = sInv;

    // ---- normalized write, float4-coalesced ----
    #pragma unroll
    for (int j = 0; j < VPT; ++j) {
        float4 o;
        float x0 = k2f(key[4*j+0]); o.x = fmaxf(x0 - thr, 0.0f) * __expf(x0) * inv;
        float x1 = k2f(key[4*j+1]); o.y = fmaxf(x1 - thr, 0.0f) * __expf(x1) * inv;
        float x2 = k2f(key[4*j+2]); o.z = fmaxf(x2 - thr, 0.0f) * __expf(x2) * inv;
        float x3 = k2f(key[4*j+3]); o.w = fmaxf(x3 - thr, 0.0f) * __expf(x3) * inv;
        out4[t + j * TPB] = o;
    }
}

extern "C" void kernel_launch(void* const* d_in, const int* in_sizes, int n_in,
                              void* d_out, int out_size, void* d_ws, size_t ws_size,
                              hipStream_t stream)
{
    const float* in   = (const float*)d_in[0];
    const float* rate = (const float*)d_in[1];
    float*       out  = (float*)d_out;
    rsoftmax_kernel<<<dim3(ROWS), dim3(TPB), 0, stream>>>(in, rate, out);
}